// Round 3
// baseline (502.143 us; speedup 1.0000x reference)
//
#include <hip/hip_runtime.h>
#include <math.h>

#define NV 196608
#define NDEG 9
#define NC 64
#define NK 8
#define TILE 64
#define NBLK (NV / TILE)   // 3072
#define SLOT ((size_t)NV * NC)
static constexpr float EPS = 1e-5f;

typedef __attribute__((ext_vector_type(8))) short bf16x8;
typedef __attribute__((ext_vector_type(4))) short bf16x4;
typedef __attribute__((ext_vector_type(4))) float f32x4;
typedef int   i32x4u __attribute__((ext_vector_type(4), aligned(4)));
typedef float f32x4u __attribute__((ext_vector_type(4), aligned(4)));

// float -> bf16 bits, round-to-nearest-even (finite inputs)
__device__ __forceinline__ short f2bf(float f) {
    unsigned u = __float_as_uint(f);
    unsigned r = (u + 0x7fffu + ((u >> 16) & 1u)) >> 16;
    return (short)r;
}
__device__ __forceinline__ float bf2f(short h) {
    return __uint_as_float(((unsigned)(unsigned short)h) << 16);
}

// exact mish: h * tanh(softplus(h)); tanh(ln(p)) = (p^2-1)/(p^2+1), p = 1+e^h
__device__ __forceinline__ float mish_f(float h) {
    float t = __expf(fminf(h, 20.f));
    float p = 1.f + t;
    float p2 = p * p;
    return h * ((p2 - 1.f) / (p2 + 1.f));
}

// LDS tile address: row-stride 64 shorts, 8-short chunks XOR-swizzled.
// (used only for the X7 tile now; 0 conflicts measured with this layout)
#define LDSOFF(r, c) ((r) * 64 + (((c) ^ ((r) & 7)) * 8))

// ---------------------------------------------------------------------------
// BN batch stats (blocks 0..1023) + W pre-transpose to bf16 (blocks 1024..1151).
// Wb[k][o][i] = bf16(weight[k][i][o]) -- exactly the MFMA B-fragment order.
// ---------------------------------------------------------------------------
__global__ void __launch_bounds__(256) stats_wconv_kernel(
    const float* __restrict__ x, float* __restrict__ stats,
    const float* __restrict__ w, unsigned short* __restrict__ Wb) {
    if (blockIdx.x >= 1024) {
        int idx = (blockIdx.x - 1024) * 256 + threadIdx.x;   // 32768 elements
        int i = idx & 63, o = (idx >> 6) & 63, k = idx >> 12;
        Wb[idx] = (unsigned short)f2bf(w[k * 4096 + i * 64 + o]);
        return;
    }
    const float4* x4 = (const float4*)x;
    int t = blockIdx.x * 256 + threadIdx.x;
    int stride = 1024 * 256;
    float4 s = {0.f, 0.f, 0.f, 0.f}, ss = {0.f, 0.f, 0.f, 0.f};
    for (int i = t; i < NV * (NC / 4); i += stride) {
        float4 v = x4[i];
        s.x += v.x; s.y += v.y; s.z += v.z; s.w += v.w;
        ss.x += v.x * v.x; ss.y += v.y * v.y; ss.z += v.z * v.z; ss.w += v.w * v.w;
    }
    __shared__ float4 ls[256], lss[256];
    ls[threadIdx.x] = s;
    lss[threadIdx.x] = ss;
    __syncthreads();
    if (threadIdx.x < 64) {
        int ch = threadIdx.x;
        int g = ch >> 2, comp = ch & 3;
        float a = 0.f, b = 0.f;
        #pragma unroll
        for (int k = 0; k < 16; ++k) {
            float4 v1 = ls[k * 16 + g];
            float4 v2 = lss[k * 16 + g];
            a += (comp == 0) ? v1.x : (comp == 1) ? v1.y : (comp == 2) ? v1.z : v1.w;
            b += (comp == 0) ? v2.x : (comp == 1) ? v2.y : (comp == 2) ? v2.z : v2.w;
        }
        atomicAdd(&stats[ch], a);
        atomicAdd(&stats[64 + ch], b);
    }
}

// ---------------------------------------------------------------------------
// k=0: BN apply + Mish -> basis slot 0 (bf16). Pure elementwise.
// ---------------------------------------------------------------------------
__global__ void __launch_bounds__(256) bn_mish_k0(
    const float* __restrict__ x, const float* __restrict__ stats,
    const float* __restrict__ gamma, const float* __restrict__ beta,
    unsigned short* __restrict__ dst) {
    int lane = threadIdx.x & 63;
    int wave = threadIdx.x >> 6;
    int c4 = lane & 15, rg = lane >> 4;
    int tile0 = blockIdx.x * TILE;

    float4 sc, sh;
    {
        float4 su = ((const float4*)stats)[c4];
        float4 sq = ((const float4*)stats)[16 + c4];
        float4 g4 = ((const float4*)gamma)[c4];
        float4 b4 = ((const float4*)beta)[c4];
        #define BNC(comp) { float mu = su.comp * (1.f / NV);                     \
                            float va = sq.comp * (1.f / NV) - mu * mu;           \
                            float rs = rsqrtf(va + EPS);                         \
                            sc.comp = g4.comp * rs;                              \
                            sh.comp = b4.comp - mu * sc.comp; }
        BNC(x) BNC(y) BNC(z) BNC(w)
        #undef BNC
    }

    const float4* x4 = (const float4*)x;
    #pragma unroll
    for (int it = 0; it < 4; ++it) {
        int v = tile0 + wave * 16 + it * 4 + rg;
        float4 h = x4[v * 16 + c4];
        float4 m;
        m.x = mish_f(h.x * sc.x + sh.x);
        m.y = mish_f(h.y * sc.y + sh.y);
        m.z = mish_f(h.z * sc.z + sh.z);
        m.w = mish_f(h.w * sc.w + sh.w);
        bf16x4 xb = { f2bf(m.x), f2bf(m.y), f2bf(m.z), f2bf(m.w) };
        *(bf16x4*)(dst + (size_t)v * NC + 4 * c4) = xb;
    }
}

// ---------------------------------------------------------------------------
// One Chebyshev step, bf16 in/out, fp32 arithmetic.
//   s = L @ src; dst = FIRST ? s : 2*s - prev.
// ---------------------------------------------------------------------------
template <bool FIRST>
__global__ void __launch_bounds__(256) cheb_step(
    const int* __restrict__ cols, const float* __restrict__ vals,
    const unsigned short* __restrict__ src, const unsigned short* __restrict__ prev,
    unsigned short* __restrict__ dst) {
    int lane = threadIdx.x & 63;
    int wave = threadIdx.x >> 6;
    int c8 = lane & 7, rg = lane >> 3;
    int tile0 = blockIdx.x * TILE;

    #pragma unroll
    for (int it = 0; it < 2; ++it) {
        int v = tile0 + wave * 16 + it * 8 + rg;
        const int* cp = cols + v * NDEG;
        const float* vp = vals + v * NDEG;
        i32x4u c03 = *(const i32x4u*)cp;
        i32x4u c47 = *(const i32x4u*)(cp + 4);
        int    cl8 = cp[8];
        f32x4u a03 = *(const f32x4u*)vp;
        f32x4u a47 = *(const f32x4u*)(vp + 4);
        float  al8 = vp[8];

        int   cj[NDEG] = { c03[0], c03[1], c03[2], c03[3],
                           c47[0], c47[1], c47[2], c47[3], cl8 };
        float aj[NDEG] = { a03[0], a03[1], a03[2], a03[3],
                           a47[0], a47[1], a47[2], a47[3], al8 };

        bf16x8 g[NDEG];
        #pragma unroll
        for (int j = 0; j < NDEG; ++j)
            g[j] = *(const bf16x8*)(src + (size_t)cj[j] * NC + c8 * 8);

        float s[8] = {0.f, 0.f, 0.f, 0.f, 0.f, 0.f, 0.f, 0.f};
        #pragma unroll
        for (int j = 0; j < NDEG; ++j)
            #pragma unroll
            for (int q = 0; q < 8; ++q) s[q] += aj[j] * bf2f(g[j][q]);

        bf16x8 xb;
        if (FIRST) {
            #pragma unroll
            for (int q = 0; q < 8; ++q) xb[q] = f2bf(s[q]);
        } else {
            bf16x8 p = __builtin_nontemporal_load(
                           (const bf16x8*)(prev + (size_t)v * NC + c8 * 8));
            #pragma unroll
            for (int q = 0; q < 8; ++q) xb[q] = f2bf(2.f * s[q] - bf2f(p[q]));
        }
        *(bf16x8*)(dst + (size_t)v * NC + c8 * 8) = xb;
    }
}

// ---------------------------------------------------------------------------
// FUSED final dispatch: Chebyshev step k=7 (slot 7 kept in LDS only) + full
// einsum over k=0..7 with bias.
// LDS-free einsum: each A-fragment byte is consumed exactly once per k and the
// per-lane direct read (basis[row*64 + qq*8]) is already 16-full-line coalesced,
// so LDS staging bought zero reuse; W (64 KB) is L1/L2-hot -> direct fragment
// reads. LDS = 8 KB (X7 only), ONE barrier, no per-k sync -> high occupancy,
// waves free-run the 256 MB HBM stream. Register double-buffer on A (k+1
// issued before MFMAs of k, nontemporal: each byte read once).
// ---------------------------------------------------------------------------
__global__ void __launch_bounds__(256) cheb7_gemm(
    const int* __restrict__ cols, const float* __restrict__ vals,
    const unsigned short* __restrict__ basis, const unsigned short* __restrict__ Wb,
    const float* __restrict__ bias, float* __restrict__ out) {
    __shared__ __align__(16) short X7[NC * NC];      // 8 KB only

    const int tid  = threadIdx.x;
    const int lane = tid & 63;
    const int wave = tid >> 6;
    const int c8 = lane & 7, rg = lane >> 3;         // cheb mapping
    const int m16 = lane & 15, qq = lane >> 4;       // MFMA fragment mapping
    const int tile0 = blockIdx.x * TILE;

    // own A row for the einsum (same fragment values as the old LDS path)
    const unsigned short* aptr = basis + (size_t)(tile0 + wave * 16 + m16) * NC;

    // ---- prologue: k=0 A-fragments in flight across the gather phase ----
    bf16x8 a0 = __builtin_nontemporal_load((const bf16x8*)(aptr + qq * 8));
    bf16x8 a1 = __builtin_nontemporal_load((const bf16x8*)(aptr + 32 + qq * 8));

    // ---- phase 1: Chebyshev k=7 for own rows -> X7 (LDS), no global write ----
    {
        const unsigned short* src = basis + (size_t)6 * SLOT;
        const unsigned short* prv = basis + (size_t)5 * SLOT;
        #pragma unroll
        for (int it = 0; it < 2; ++it) {
            int r = wave * 16 + it * 8 + rg;
            int v = tile0 + r;
            const int* cp = cols + v * NDEG;
            const float* vp = vals + v * NDEG;
            i32x4u c03 = *(const i32x4u*)cp;
            i32x4u c47 = *(const i32x4u*)(cp + 4);
            int    cl8 = cp[8];
            f32x4u a03 = *(const f32x4u*)vp;
            f32x4u a47 = *(const f32x4u*)(vp + 4);
            float  al8 = vp[8];

            int   cj[NDEG] = { c03[0], c03[1], c03[2], c03[3],
                               c47[0], c47[1], c47[2], c47[3], cl8 };
            float aj[NDEG] = { a03[0], a03[1], a03[2], a03[3],
                               a47[0], a47[1], a47[2], a47[3], al8 };

            bf16x8 g[NDEG];
            #pragma unroll
            for (int j = 0; j < NDEG; ++j)
                g[j] = *(const bf16x8*)(src + (size_t)cj[j] * NC + c8 * 8);

            float s[8] = {0.f, 0.f, 0.f, 0.f, 0.f, 0.f, 0.f, 0.f};
            #pragma unroll
            for (int j = 0; j < NDEG; ++j)
                #pragma unroll
                for (int q = 0; q < 8; ++q) s[q] += aj[j] * bf2f(g[j][q]);

            // plain (cached) prev load: slot 5 rows are re-read by einsum k=5
            bf16x8 p = *(const bf16x8*)(prv + (size_t)v * NC + c8 * 8);
            bf16x8 xb;
            #pragma unroll
            for (int q = 0; q < 8; ++q) xb[q] = f2bf(2.f * s[q] - bf2f(p[q]));
            *(bf16x8*)&X7[LDSOFF(r, c8)] = xb;
        }
    }
    __syncthreads();   // the only barrier: X7 ready

    // ---- phase 2: einsum k=0..7, barrier-free, reg-double-buffered A ----
    f32x4 acc[4];
    #pragma unroll
    for (int nt = 0; nt < 4; ++nt) acc[nt] = (f32x4){0.f, 0.f, 0.f, 0.f};

    #pragma unroll
    for (int k = 0; k < NK; ++k) {
        bf16x8 na0, na1;
        if (k + 1 < NK - 1) {   // prefetch A for k+1 (slot 7 comes from X7)
            const unsigned short* ap = aptr + (size_t)(k + 1) * SLOT;
            na0 = __builtin_nontemporal_load((const bf16x8*)(ap + qq * 8));
            na1 = __builtin_nontemporal_load((const bf16x8*)(ap + 32 + qq * 8));
        }
        const unsigned short* wk = Wb + k * NC * NC;
        #pragma unroll
        for (int nt = 0; nt < 4; ++nt) {
            const unsigned short* wr = wk + (nt * 16 + m16) * NC;
            bf16x8 b0 = *(const bf16x8*)(wr + qq * 8);
            bf16x8 b1 = *(const bf16x8*)(wr + 32 + qq * 8);
            acc[nt] = __builtin_amdgcn_mfma_f32_16x16x32_bf16(a0, b0, acc[nt], 0, 0, 0);
            acc[nt] = __builtin_amdgcn_mfma_f32_16x16x32_bf16(a1, b1, acc[nt], 0, 0, 0);
        }
        if (k + 1 < NK - 1) {
            a0 = na0; a1 = na1;
        } else if (k + 1 == NK - 1) {   // next is k=7: A from X7
            a0 = *(const bf16x8*)&X7[LDSOFF(wave * 16 + m16, qq)];
            a1 = *(const bf16x8*)&X7[LDSOFF(wave * 16 + m16, qq + 4)];
        }
    }

    #pragma unroll
    for (int nt = 0; nt < 4; ++nt) {
        float bcol = bias[nt * 16 + m16];
        #pragma unroll
        for (int r = 0; r < 4; ++r) {
            int vout = tile0 + wave * 16 + qq * 4 + r;
            out[(size_t)vout * NC + nt * 16 + m16] = acc[nt][r] + bcol;
        }
    }
}

// ---------------------------------------------------------------------------
// Fallback einsum (small-ws path only): LDS-free grouped gemm.
// ---------------------------------------------------------------------------
__global__ void __launch_bounds__(256) gemm_bases(
    const unsigned short* __restrict__ basis, const unsigned short* __restrict__ Wb,
    const float* __restrict__ bias, float* __restrict__ out,
    int kb, int kc, int S, int first) {
    int lane = threadIdx.x & 63;
    int wave = threadIdx.x >> 6;
    int m16 = lane & 15, qq = lane >> 4;
    int tile0 = blockIdx.x * TILE;

    f32x4 acc[4];
    #pragma unroll
    for (int nt = 0; nt < 4; ++nt) acc[nt] = (f32x4){0.f, 0.f, 0.f, 0.f};

    #pragma unroll 1
    for (int j = 0; j < kc; ++j) {
        int k = kb + j;
        const unsigned short* bs =
            basis + (size_t)(k % S) * SLOT + (size_t)(tile0 + wave * 16 + m16) * NC;
        bf16x8 a0 = *(const bf16x8*)(bs + qq * 8);
        bf16x8 a1 = *(const bf16x8*)(bs + 32 + qq * 8);
        const unsigned short* wk = Wb + (size_t)k * NC * NC;
        #pragma unroll
        for (int nt = 0; nt < 4; ++nt) {
            const unsigned short* wr = wk + (nt * 16 + m16) * NC;
            bf16x8 b0 = *(const bf16x8*)(wr + qq * 8);
            bf16x8 b1 = *(const bf16x8*)(wr + 32 + qq * 8);
            acc[nt] = __builtin_amdgcn_mfma_f32_16x16x32_bf16(a0, b0, acc[nt], 0, 0, 0);
            acc[nt] = __builtin_amdgcn_mfma_f32_16x16x32_bf16(a1, b1, acc[nt], 0, 0, 0);
        }
    }

    #pragma unroll
    for (int nt = 0; nt < 4; ++nt) {
        float bcol = bias[nt * 16 + m16];
        #pragma unroll
        for (int r = 0; r < 4; ++r) {
            int vout = tile0 + wave * 16 + qq * 4 + r;
            float* po = out + (size_t)vout * NC + nt * 16 + m16;
            *po = first ? (acc[nt][r] + bcol) : (*po + acc[nt][r]);
        }
    }
}

// ---------------------------------------------------------------------------
// Inputs: (x, lap_rows, lap_cols, lap_vals, gamma, beta, weight, bias).
// lap_rows redundant (row-sorted, 9 nnz/row). cols delivered as int32.
// ws: stats[128]f32 @0 | Wb bf16[8*64*64] @1 KiB | basis ring @128 KiB.
// Primary path (S>=7): slots 0..6 materialized, slot 7 fused into final
// cheb7_gemm dispatch (LDS-only).
// ---------------------------------------------------------------------------
extern "C" void kernel_launch(void* const* d_in, const int* in_sizes, int n_in,
                              void* d_out, int out_size, void* d_ws, size_t ws_size,
                              hipStream_t stream) {
    const float* x      = (const float*)d_in[0];
    const int*   cols   = (const int*)  d_in[2];
    const float* vals   = (const float*)d_in[3];
    const float* gamma  = (const float*)d_in[4];
    const float* beta   = (const float*)d_in[5];
    const float* weight = (const float*)d_in[6];
    const float* bias   = (const float*)d_in[7];
    float* out = (float*)d_out;

    char* wsb = (char*)d_ws;
    float*          stats = (float*)wsb;
    unsigned short* Wb    = (unsigned short*)(wsb + 1024);
    unsigned short* basis = (unsigned short*)(wsb + 131072);

    long long Sll = ((long long)ws_size - 131072) / (long long)(SLOT * sizeof(unsigned short));
    int S = (Sll < 0) ? 0 : (int)Sll;
    if (S > NK) S = NK;
    if (S < 3) S = 3;

    hipMemsetAsync(stats, 0, 1024, stream);
    stats_wconv_kernel<<<1152, 256, 0, stream>>>(x, stats, weight, Wb);
    bn_mish_k0<<<NBLK, 256, 0, stream>>>(x, stats, gamma, beta, basis);  // slot 0

    if (S >= 7) {
        // slots 1..6 materialized; k=7 fused into the final gemm dispatch
        for (int k = 1; k < NK - 1; ++k) {
            const unsigned short* src = basis + (size_t)(k - 1) * SLOT;
            unsigned short*       dst = basis + (size_t)k * SLOT;
            if (k == 1) {
                cheb_step<true><<<NBLK, 256, 0, stream>>>(cols, vals, src, src, dst);
            } else {
                const unsigned short* prev = basis + (size_t)(k - 2) * SLOT;
                cheb_step<false><<<NBLK, 256, 0, stream>>>(cols, vals, src, prev, dst);
            }
        }
        cheb7_gemm<<<NBLK, 256, 0, stream>>>(cols, vals, basis, Wb, bias, out);
    } else {
        int kb = 0, gsize = S, first = 1;
        while (kb < NK) {
            int kc = (gsize < NK - kb) ? gsize : (NK - kb);
            for (int k = (kb == 0 ? 1 : kb); k < kb + kc; ++k) {
                const unsigned short* src = basis + (size_t)((k - 1) % S) * SLOT;
                unsigned short*       dst = basis + (size_t)(k % S) * SLOT;
                if (k == 1) {
                    cheb_step<true><<<NBLK, 256, 0, stream>>>(cols, vals, src, src, dst);
                } else {
                    const unsigned short* prev = basis + (size_t)((k - 2) % S) * SLOT;
                    cheb_step<false><<<NBLK, 256, 0, stream>>>(cols, vals, src, prev, dst);
                }
            }
            gemm_bases<<<NBLK, 256, 0, stream>>>(basis, Wb, bias, out, kb, kc, S, first);
            first = 0;
            kb += kc;
            gsize = S - 2;
        }
    }
}

// Round 4
// 445.210 us; speedup vs baseline: 1.1279x; 1.1279x over previous
//
#include <hip/hip_runtime.h>
#include <math.h>

#define NV 196608
#define NDEG 9
#define NC 64
#define NK 8
#define TILE 64
#define NBLK (NV / TILE)   // 3072
#define SLOT ((size_t)NV * NC)
static constexpr float EPS = 1e-5f;

typedef __attribute__((ext_vector_type(8))) short bf16x8;
typedef __attribute__((ext_vector_type(4))) short bf16x4;
typedef __attribute__((ext_vector_type(4))) float f32x4;
typedef int   i32x4u __attribute__((ext_vector_type(4), aligned(4)));
typedef float f32x4u __attribute__((ext_vector_type(4), aligned(4)));

// float -> bf16 bits, round-to-nearest-even (finite inputs)
__device__ __forceinline__ short f2bf(float f) {
    unsigned u = __float_as_uint(f);
    unsigned r = (u + 0x7fffu + ((u >> 16) & 1u)) >> 16;
    return (short)r;
}
__device__ __forceinline__ float bf2f(short h) {
    return __uint_as_float(((unsigned)(unsigned short)h) << 16);
}

// exact mish: h * tanh(softplus(h)); tanh(ln(p)) = (p^2-1)/(p^2+1), p = 1+e^h
__device__ __forceinline__ float mish_f(float h) {
    float t = __expf(fminf(h, 20.f));
    float p = 1.f + t;
    float p2 = p * p;
    return h * ((p2 - 1.f) / (p2 + 1.f));
}

// LDS tile address: row-stride 64 shorts, 8-short chunks XOR-swizzled.
// 0 conflicts measured with this layout (prior session round 6).
#define LDSOFF(r, c) ((r) * 64 + (((c) ^ ((r) & 7)) * 8))

// ---------------------------------------------------------------------------
// BN batch stats (blocks 0..1023) + W pre-transpose to bf16 (blocks 1024..1151).
// Wb[k][o][i] = bf16(weight[k][i][o]) -- exactly the MFMA B-fragment order.
// ---------------------------------------------------------------------------
__global__ void __launch_bounds__(256) stats_wconv_kernel(
    const float* __restrict__ x, float* __restrict__ stats,
    const float* __restrict__ w, unsigned short* __restrict__ Wb) {
    if (blockIdx.x >= 1024) {
        int idx = (blockIdx.x - 1024) * 256 + threadIdx.x;   // 32768 elements
        int i = idx & 63, o = (idx >> 6) & 63, k = idx >> 12;
        Wb[idx] = (unsigned short)f2bf(w[k * 4096 + i * 64 + o]);
        return;
    }
    const float4* x4 = (const float4*)x;
    int t = blockIdx.x * 256 + threadIdx.x;
    int stride = 1024 * 256;
    float4 s = {0.f, 0.f, 0.f, 0.f}, ss = {0.f, 0.f, 0.f, 0.f};
    for (int i = t; i < NV * (NC / 4); i += stride) {
        float4 v = x4[i];
        s.x += v.x; s.y += v.y; s.z += v.z; s.w += v.w;
        ss.x += v.x * v.x; ss.y += v.y * v.y; ss.z += v.z * v.z; ss.w += v.w * v.w;
    }
    __shared__ float4 ls[256], lss[256];
    ls[threadIdx.x] = s;
    lss[threadIdx.x] = ss;
    __syncthreads();
    if (threadIdx.x < 64) {
        int ch = threadIdx.x;
        int g = ch >> 2, comp = ch & 3;
        float a = 0.f, b = 0.f;
        #pragma unroll
        for (int k = 0; k < 16; ++k) {
            float4 v1 = ls[k * 16 + g];
            float4 v2 = lss[k * 16 + g];
            a += (comp == 0) ? v1.x : (comp == 1) ? v1.y : (comp == 2) ? v1.z : v1.w;
            b += (comp == 0) ? v2.x : (comp == 1) ? v2.y : (comp == 2) ? v2.z : v2.w;
        }
        atomicAdd(&stats[ch], a);
        atomicAdd(&stats[64 + ch], b);
    }
}

// ---------------------------------------------------------------------------
// k=0: BN apply + Mish -> basis slot 0 (bf16). Pure elementwise.
// ---------------------------------------------------------------------------
__global__ void __launch_bounds__(256) bn_mish_k0(
    const float* __restrict__ x, const float* __restrict__ stats,
    const float* __restrict__ gamma, const float* __restrict__ beta,
    unsigned short* __restrict__ dst) {
    int lane = threadIdx.x & 63;
    int wave = threadIdx.x >> 6;
    int c4 = lane & 15, rg = lane >> 4;
    int tile0 = blockIdx.x * TILE;

    float4 sc, sh;
    {
        float4 su = ((const float4*)stats)[c4];
        float4 sq = ((const float4*)stats)[16 + c4];
        float4 g4 = ((const float4*)gamma)[c4];
        float4 b4 = ((const float4*)beta)[c4];
        #define BNC(comp) { float mu = su.comp * (1.f / NV);                     \
                            float va = sq.comp * (1.f / NV) - mu * mu;           \
                            float rs = rsqrtf(va + EPS);                         \
                            sc.comp = g4.comp * rs;                              \
                            sh.comp = b4.comp - mu * sc.comp; }
        BNC(x) BNC(y) BNC(z) BNC(w)
        #undef BNC
    }

    const float4* x4 = (const float4*)x;
    #pragma unroll
    for (int it = 0; it < 4; ++it) {
        int v = tile0 + wave * 16 + it * 4 + rg;
        float4 h = x4[v * 16 + c4];
        float4 m;
        m.x = mish_f(h.x * sc.x + sh.x);
        m.y = mish_f(h.y * sc.y + sh.y);
        m.z = mish_f(h.z * sc.z + sh.z);
        m.w = mish_f(h.w * sc.w + sh.w);
        bf16x4 xb = { f2bf(m.x), f2bf(m.y), f2bf(m.z), f2bf(m.w) };
        *(bf16x4*)(dst + (size_t)v * NC + 4 * c4) = xb;
    }
}

// ---------------------------------------------------------------------------
// One Chebyshev step, bf16 in/out, fp32 arithmetic.
//   s = L @ src; dst = FIRST ? s : 2*s - prev.
// ---------------------------------------------------------------------------
template <bool FIRST>
__global__ void __launch_bounds__(256) cheb_step(
    const int* __restrict__ cols, const float* __restrict__ vals,
    const unsigned short* __restrict__ src, const unsigned short* __restrict__ prev,
    unsigned short* __restrict__ dst) {
    int lane = threadIdx.x & 63;
    int wave = threadIdx.x >> 6;
    int c8 = lane & 7, rg = lane >> 3;
    int tile0 = blockIdx.x * TILE;

    #pragma unroll
    for (int it = 0; it < 2; ++it) {
        int v = tile0 + wave * 16 + it * 8 + rg;
        const int* cp = cols + v * NDEG;
        const float* vp = vals + v * NDEG;
        i32x4u c03 = *(const i32x4u*)cp;
        i32x4u c47 = *(const i32x4u*)(cp + 4);
        int    cl8 = cp[8];
        f32x4u a03 = *(const f32x4u*)vp;
        f32x4u a47 = *(const f32x4u*)(vp + 4);
        float  al8 = vp[8];

        int   cj[NDEG] = { c03[0], c03[1], c03[2], c03[3],
                           c47[0], c47[1], c47[2], c47[3], cl8 };
        float aj[NDEG] = { a03[0], a03[1], a03[2], a03[3],
                           a47[0], a47[1], a47[2], a47[3], al8 };

        bf16x8 g[NDEG];
        #pragma unroll
        for (int j = 0; j < NDEG; ++j)
            g[j] = *(const bf16x8*)(src + (size_t)cj[j] * NC + c8 * 8);

        float s[8] = {0.f, 0.f, 0.f, 0.f, 0.f, 0.f, 0.f, 0.f};
        #pragma unroll
        for (int j = 0; j < NDEG; ++j)
            #pragma unroll
            for (int q = 0; q < 8; ++q) s[q] += aj[j] * bf2f(g[j][q]);

        bf16x8 xb;
        if (FIRST) {
            #pragma unroll
            for (int q = 0; q < 8; ++q) xb[q] = f2bf(s[q]);
        } else {
            bf16x8 p = __builtin_nontemporal_load(
                           (const bf16x8*)(prev + (size_t)v * NC + c8 * 8));
            #pragma unroll
            for (int q = 0; q < 8; ++q) xb[q] = f2bf(2.f * s[q] - bf2f(p[q]));
        }
        *(bf16x8*)(dst + (size_t)v * NC + c8 * 8) = xb;
    }
}

// ---------------------------------------------------------------------------
// FUSED final dispatch: Chebyshev step k=7 (slot 7 kept in LDS only) + full
// einsum over k=0..7 with bias.
// Round-4 structure (fixes round-3 vmcnt hazard):
//   - A fragments: direct per-lane nontemporal global loads, register
//     double-buffered one FULL iteration ahead. MFMA consumes A regs that
//     retired last iteration (only 4 younger vmem ops outstanding -> counted
//     vmcnt, no HBM stall on the critical path).
//   - W fragments: LDS double-buffer (lgkmcnt domain, never in the MFMA's
//     vmcnt path). ds_write of W(k+1) + one barrier per k, as in round 2.
//   - X7: LDS, swizzled, one extra barrier after the gather phase.
// LDS = 8 (X7) + 16 (Wl x2) = 24 KB -> 6 blocks/CU headroom (round 2: 40 KB).
// ---------------------------------------------------------------------------
__global__ void __launch_bounds__(256) cheb7_gemm(
    const int* __restrict__ cols, const float* __restrict__ vals,
    const unsigned short* __restrict__ basis, const unsigned short* __restrict__ Wb,
    const float* __restrict__ bias, float* __restrict__ out) {
    __shared__ __align__(16) short X7[NC * NC];      // 8 KB
    __shared__ __align__(16) short Wl[2][NC * NC];   // 2 x 8 KB

    const int tid  = threadIdx.x;
    const int lane = tid & 63;
    const int wave = tid >> 6;
    const int c8 = lane & 7, rg = lane >> 3;         // cheb mapping
    const int m16 = lane & 15, qq = lane >> 4;       // MFMA fragment mapping
    const int tile0 = blockIdx.x * TILE;
    const int rW = tid >> 3, cW = tid & 7;           // W staging mapping

    // own A row for the einsum (same fragment values as the LDS path)
    const unsigned short* aptr = basis + (size_t)(tile0 + wave * 16 + m16) * NC;

    // ---- prologue: A(0) regs + W(0) staged; all in flight across gathers ----
    bf16x8 a0 = __builtin_nontemporal_load((const bf16x8*)(aptr + qq * 8));
    bf16x8 a1 = __builtin_nontemporal_load((const bf16x8*)(aptr + 32 + qq * 8));
    {
        bf16x8 w0 = *(const bf16x8*)(Wb + rW * NC + cW * 8);
        bf16x8 w1 = *(const bf16x8*)(Wb + (rW + 32) * NC + cW * 8);
        *(bf16x8*)&Wl[0][LDSOFF(rW, cW)] = w0;
        *(bf16x8*)&Wl[0][LDSOFF(rW + 32, cW)] = w1;
    }

    // ---- phase 1: Chebyshev k=7 for own rows -> X7 (LDS), no global write ----
    {
        const unsigned short* src = basis + (size_t)6 * SLOT;
        const unsigned short* prv = basis + (size_t)5 * SLOT;
        #pragma unroll
        for (int it = 0; it < 2; ++it) {
            int r = wave * 16 + it * 8 + rg;
            int v = tile0 + r;
            const int* cp = cols + v * NDEG;
            const float* vp = vals + v * NDEG;
            i32x4u c03 = *(const i32x4u*)cp;
            i32x4u c47 = *(const i32x4u*)(cp + 4);
            int    cl8 = cp[8];
            f32x4u a03 = *(const f32x4u*)vp;
            f32x4u a47 = *(const f32x4u*)(vp + 4);
            float  al8 = vp[8];

            int   cj[NDEG] = { c03[0], c03[1], c03[2], c03[3],
                               c47[0], c47[1], c47[2], c47[3], cl8 };
            float aj[NDEG] = { a03[0], a03[1], a03[2], a03[3],
                               a47[0], a47[1], a47[2], a47[3], al8 };

            bf16x8 g[NDEG];
            #pragma unroll
            for (int j = 0; j < NDEG; ++j)
                g[j] = *(const bf16x8*)(src + (size_t)cj[j] * NC + c8 * 8);

            float s[8] = {0.f, 0.f, 0.f, 0.f, 0.f, 0.f, 0.f, 0.f};
            #pragma unroll
            for (int j = 0; j < NDEG; ++j)
                #pragma unroll
                for (int q = 0; q < 8; ++q) s[q] += aj[j] * bf2f(g[j][q]);

            // plain (cached) prev load: slot 5 rows are re-read by einsum k=5
            bf16x8 p = *(const bf16x8*)(prv + (size_t)v * NC + c8 * 8);
            bf16x8 xb;
            #pragma unroll
            for (int q = 0; q < 8; ++q) xb[q] = f2bf(2.f * s[q] - bf2f(p[q]));
            *(bf16x8*)&X7[LDSOFF(r, c8)] = xb;
        }
    }
    __syncthreads();   // X7 + Wl[0] ready

    // ---- phase 2: einsum k=0..7; A reg-dbuf (vmcnt), W LDS-dbuf (lgkmcnt) ----
    f32x4 acc[4];
    #pragma unroll
    for (int nt = 0; nt < 4; ++nt) acc[nt] = (f32x4){0.f, 0.f, 0.f, 0.f};

    #pragma unroll
    for (int k = 0; k < NK; ++k) {
        bf16x8 na0, na1, nw0, nw1;
        if (k + 1 < NK) {
            if (k + 1 < NK - 1) {   // A(k+1); slot 7 comes from X7
                const unsigned short* ap = aptr + (size_t)(k + 1) * SLOT;
                na0 = __builtin_nontemporal_load((const bf16x8*)(ap + qq * 8));
                na1 = __builtin_nontemporal_load((const bf16x8*)(ap + 32 + qq * 8));
            }
            const unsigned short* wp = Wb + (k + 1) * NC * NC;
            nw0 = *(const bf16x8*)(wp + rW * NC + cW * 8);
            nw1 = *(const bf16x8*)(wp + (rW + 32) * NC + cW * 8);
        }
        // MFMAs: A from regs (retired last iter), W from LDS (lgkmcnt only)
        const short* wb = Wl[k & 1];
        #pragma unroll
        for (int nt = 0; nt < 4; ++nt) {
            int o = nt * 16 + m16;
            bf16x8 b0 = *(const bf16x8*)&wb[LDSOFF(o, qq)];
            bf16x8 b1 = *(const bf16x8*)&wb[LDSOFF(o, qq + 4)];
            acc[nt] = __builtin_amdgcn_mfma_f32_16x16x32_bf16(a0, b0, acc[nt], 0, 0, 0);
            acc[nt] = __builtin_amdgcn_mfma_f32_16x16x32_bf16(a1, b1, acc[nt], 0, 0, 0);
        }
        if (k + 1 < NK) {
            short* wn = Wl[(k + 1) & 1];
            *(bf16x8*)&wn[LDSOFF(rW, cW)] = nw0;
            *(bf16x8*)&wn[LDSOFF(rW + 32, cW)] = nw1;
            __syncthreads();
            if (k + 1 < NK - 1) {
                a0 = na0; a1 = na1;
            } else {                 // next is k=7: A from X7
                a0 = *(const bf16x8*)&X7[LDSOFF(wave * 16 + m16, qq)];
                a1 = *(const bf16x8*)&X7[LDSOFF(wave * 16 + m16, qq + 4)];
            }
        }
    }

    #pragma unroll
    for (int nt = 0; nt < 4; ++nt) {
        float bcol = bias[nt * 16 + m16];
        #pragma unroll
        for (int r = 0; r < 4; ++r) {
            int vout = tile0 + wave * 16 + qq * 4 + r;
            out[(size_t)vout * NC + nt * 16 + m16] = acc[nt][r] + bcol;
        }
    }
}

// ---------------------------------------------------------------------------
// Fallback einsum (small-ws path only): LDS-free grouped gemm.
// ---------------------------------------------------------------------------
__global__ void __launch_bounds__(256) gemm_bases(
    const unsigned short* __restrict__ basis, const unsigned short* __restrict__ Wb,
    const float* __restrict__ bias, float* __restrict__ out,
    int kb, int kc, int S, int first) {
    int lane = threadIdx.x & 63;
    int wave = threadIdx.x >> 6;
    int m16 = lane & 15, qq = lane >> 4;
    int tile0 = blockIdx.x * TILE;

    f32x4 acc[4];
    #pragma unroll
    for (int nt = 0; nt < 4; ++nt) acc[nt] = (f32x4){0.f, 0.f, 0.f, 0.f};

    #pragma unroll 1
    for (int j = 0; j < kc; ++j) {
        int k = kb + j;
        const unsigned short* bs =
            basis + (size_t)(k % S) * SLOT + (size_t)(tile0 + wave * 16 + m16) * NC;
        bf16x8 a0 = *(const bf16x8*)(bs + qq * 8);
        bf16x8 a1 = *(const bf16x8*)(bs + 32 + qq * 8);
        const unsigned short* wk = Wb + (size_t)k * NC * NC;
        #pragma unroll
        for (int nt = 0; nt < 4; ++nt) {
            const unsigned short* wr = wk + (nt * 16 + m16) * NC;
            bf16x8 b0 = *(const bf16x8*)(wr + qq * 8);
            bf16x8 b1 = *(const bf16x8*)(wr + 32 + qq * 8);
            acc[nt] = __builtin_amdgcn_mfma_f32_16x16x32_bf16(a0, b0, acc[nt], 0, 0, 0);
            acc[nt] = __builtin_amdgcn_mfma_f32_16x16x32_bf16(a1, b1, acc[nt], 0, 0, 0);
        }
    }

    #pragma unroll
    for (int nt = 0; nt < 4; ++nt) {
        float bcol = bias[nt * 16 + m16];
        #pragma unroll
        for (int r = 0; r < 4; ++r) {
            int vout = tile0 + wave * 16 + qq * 4 + r;
            float* po = out + (size_t)vout * NC + nt * 16 + m16;
            *po = first ? (acc[nt][r] + bcol) : (*po + acc[nt][r]);
        }
    }
}

// ---------------------------------------------------------------------------
// Inputs: (x, lap_rows, lap_cols, lap_vals, gamma, beta, weight, bias).
// lap_rows redundant (row-sorted, 9 nnz/row). cols delivered as int32.
// ws: stats[128]f32 @0 | Wb bf16[8*64*64] @1 KiB | basis ring @128 KiB.
// Primary path (S>=7): slots 0..6 materialized, slot 7 fused into final
// cheb7_gemm dispatch (LDS-only).
// ---------------------------------------------------------------------------
extern "C" void kernel_launch(void* const* d_in, const int* in_sizes, int n_in,
                              void* d_out, int out_size, void* d_ws, size_t ws_size,
                              hipStream_t stream) {
    const float* x      = (const float*)d_in[0];
    const int*   cols   = (const int*)  d_in[2];
    const float* vals   = (const float*)d_in[3];
    const float* gamma  = (const float*)d_in[4];
    const float* beta   = (const float*)d_in[5];
    const float* weight = (const float*)d_in[6];
    const float* bias   = (const float*)d_in[7];
    float* out = (float*)d_out;

    char* wsb = (char*)d_ws;
    float*          stats = (float*)wsb;
    unsigned short* Wb    = (unsigned short*)(wsb + 1024);
    unsigned short* basis = (unsigned short*)(wsb + 131072);

    long long Sll = ((long long)ws_size - 131072) / (long long)(SLOT * sizeof(unsigned short));
    int S = (Sll < 0) ? 0 : (int)Sll;
    if (S > NK) S = NK;
    if (S < 3) S = 3;

    hipMemsetAsync(stats, 0, 1024, stream);
    stats_wconv_kernel<<<1152, 256, 0, stream>>>(x, stats, weight, Wb);
    bn_mish_k0<<<NBLK, 256, 0, stream>>>(x, stats, gamma, beta, basis);  // slot 0

    if (S >= 7) {
        // slots 1..6 materialized; k=7 fused into the final gemm dispatch
        for (int k = 1; k < NK - 1; ++k) {
            const unsigned short* src = basis + (size_t)(k - 1) * SLOT;
            unsigned short*       dst = basis + (size_t)k * SLOT;
            if (k == 1) {
                cheb_step<true><<<NBLK, 256, 0, stream>>>(cols, vals, src, src, dst);
            } else {
                const unsigned short* prev = basis + (size_t)(k - 2) * SLOT;
                cheb_step<false><<<NBLK, 256, 0, stream>>>(cols, vals, src, prev, dst);
            }
        }
        cheb7_gemm<<<NBLK, 256, 0, stream>>>(cols, vals, basis, Wb, bias, out);
    } else {
        int kb = 0, gsize = S, first = 1;
        while (kb < NK) {
            int kc = (gsize < NK - kb) ? gsize : (NK - kb);
            for (int k = (kb == 0 ? 1 : kb); k < kb + kc; ++k) {
                const unsigned short* src = basis + (size_t)((k - 1) % S) * SLOT;
                unsigned short*       dst = basis + (size_t)(k % S) * SLOT;
                if (k == 1) {
                    cheb_step<true><<<NBLK, 256, 0, stream>>>(cols, vals, src, src, dst);
                } else {
                    const unsigned short* prev = basis + (size_t)((k - 2) % S) * SLOT;
                    cheb_step<false><<<NBLK, 256, 0, stream>>>(cols, vals, src, prev, dst);
                }
            }
            gemm_bases<<<NBLK, 256, 0, stream>>>(basis, Wb, bias, out, kb, kc, S, first);
            first = 0;
            kb += kc;
            gsize = S - 2;
        }
    }
}

// Round 5
// 437.817 us; speedup vs baseline: 1.1469x; 1.0169x over previous
//
#include <hip/hip_runtime.h>
#include <math.h>

#define NV 196608
#define NDEG 9
#define NC 64
#define NK 8
#define TILE 64
#define NBLK (NV / TILE)   // 3072
#define SLOT ((size_t)NV * NC)
static constexpr float EPS = 1e-5f;

typedef __attribute__((ext_vector_type(8))) short bf16x8;
typedef __attribute__((ext_vector_type(4))) short bf16x4;
typedef __attribute__((ext_vector_type(4))) float f32x4;
typedef int   i32x4u __attribute__((ext_vector_type(4), aligned(4)));
typedef float f32x4u __attribute__((ext_vector_type(4), aligned(4)));

// float -> bf16 bits, round-to-nearest-even (finite inputs)
__device__ __forceinline__ short f2bf(float f) {
    unsigned u = __float_as_uint(f);
    unsigned r = (u + 0x7fffu + ((u >> 16) & 1u)) >> 16;
    return (short)r;
}
__device__ __forceinline__ float bf2f(short h) {
    return __uint_as_float(((unsigned)(unsigned short)h) << 16);
}

// exact mish: h * tanh(softplus(h)); tanh(ln(p)) = (p^2-1)/(p^2+1), p = 1+e^h
__device__ __forceinline__ float mish_f(float h) {
    float t = __expf(fminf(h, 20.f));
    float p = 1.f + t;
    float p2 = p * p;
    return h * ((p2 - 1.f) / (p2 + 1.f));
}

// LDS tile address: row-stride 64 shorts, 8-short chunks XOR-swizzled.
// 0 conflicts measured with this layout (prior session round 6).
#define LDSOFF(r, c) ((r) * 64 + (((c) ^ ((r) & 7)) * 8))

// ---------------------------------------------------------------------------
// Cache policy for the whole pipeline (L3 = 256 MB, footprint must fit):
//   x (50 MB)        : plain read in stats (re-read by bn), NT read in bn
//                      (dead after) -> L3 space freed for the slot ring.
//   cols/vals (14 MB): plain (re-read every step).
//   slots 0..6 (168) : plain writes, plain gather/prev reads -- must stay
//                      L3-resident for the final einsum stream. (Round-4 bug:
//                      NT prev loads marked slots 0..4 evict-first -> 200 MB
//                      HBM re-fetch in cheb7_gemm.)
//   einsum A-stream  : NT (truly dead after last read).
//   out (50 MB)      : NT stores (written once, never read).
// ---------------------------------------------------------------------------

// ---------------------------------------------------------------------------
// BN batch stats (blocks 0..1023) + W pre-transpose to bf16 (blocks 1024..1151).
// Wb[k][o][i] = bf16(weight[k][i][o]) -- exactly the MFMA B-fragment order.
// ---------------------------------------------------------------------------
__global__ void __launch_bounds__(256) stats_wconv_kernel(
    const float* __restrict__ x, float* __restrict__ stats,
    const float* __restrict__ w, unsigned short* __restrict__ Wb) {
    if (blockIdx.x >= 1024) {
        int idx = (blockIdx.x - 1024) * 256 + threadIdx.x;   // 32768 elements
        int i = idx & 63, o = (idx >> 6) & 63, k = idx >> 12;
        Wb[idx] = (unsigned short)f2bf(w[k * 4096 + i * 64 + o]);
        return;
    }
    const float4* x4 = (const float4*)x;
    int t = blockIdx.x * 256 + threadIdx.x;
    int stride = 1024 * 256;
    float4 s = {0.f, 0.f, 0.f, 0.f}, ss = {0.f, 0.f, 0.f, 0.f};
    for (int i = t; i < NV * (NC / 4); i += stride) {
        float4 v = x4[i];
        s.x += v.x; s.y += v.y; s.z += v.z; s.w += v.w;
        ss.x += v.x * v.x; ss.y += v.y * v.y; ss.z += v.z * v.z; ss.w += v.w * v.w;
    }
    __shared__ float4 ls[256], lss[256];
    ls[threadIdx.x] = s;
    lss[threadIdx.x] = ss;
    __syncthreads();
    if (threadIdx.x < 64) {
        int ch = threadIdx.x;
        int g = ch >> 2, comp = ch & 3;
        float a = 0.f, b = 0.f;
        #pragma unroll
        for (int k = 0; k < 16; ++k) {
            float4 v1 = ls[k * 16 + g];
            float4 v2 = lss[k * 16 + g];
            a += (comp == 0) ? v1.x : (comp == 1) ? v1.y : (comp == 2) ? v1.z : v1.w;
            b += (comp == 0) ? v2.x : (comp == 1) ? v2.y : (comp == 2) ? v2.z : v2.w;
        }
        atomicAdd(&stats[ch], a);
        atomicAdd(&stats[64 + ch], b);
    }
}

// ---------------------------------------------------------------------------
// k=0: BN apply + Mish -> basis slot 0 (bf16). Pure elementwise.
// x reads are NONTEMPORAL: last use of x; frees 50 MB of L3 for the slots.
// ---------------------------------------------------------------------------
__global__ void __launch_bounds__(256) bn_mish_k0(
    const float* __restrict__ x, const float* __restrict__ stats,
    const float* __restrict__ gamma, const float* __restrict__ beta,
    unsigned short* __restrict__ dst) {
    int lane = threadIdx.x & 63;
    int wave = threadIdx.x >> 6;
    int c4 = lane & 15, rg = lane >> 4;
    int tile0 = blockIdx.x * TILE;

    f32x4 sc, sh;
    {
        float4 su = ((const float4*)stats)[c4];
        float4 sq = ((const float4*)stats)[16 + c4];
        float4 g4 = ((const float4*)gamma)[c4];
        float4 b4 = ((const float4*)beta)[c4];
        #define BNC(idx, comp) { float mu = su.comp * (1.f / NV);                \
                            float va = sq.comp * (1.f / NV) - mu * mu;           \
                            float rs = rsqrtf(va + EPS);                         \
                            sc[idx] = g4.comp * rs;                              \
                            sh[idx] = b4.comp - mu * sc[idx]; }
        BNC(0, x) BNC(1, y) BNC(2, z) BNC(3, w)
        #undef BNC
    }

    const f32x4* x4 = (const f32x4*)x;
    #pragma unroll
    for (int it = 0; it < 4; ++it) {
        int v = tile0 + wave * 16 + it * 4 + rg;
        f32x4 h = __builtin_nontemporal_load(x4 + v * 16 + c4);
        float m0 = mish_f(h[0] * sc[0] + sh[0]);
        float m1 = mish_f(h[1] * sc[1] + sh[1]);
        float m2 = mish_f(h[2] * sc[2] + sh[2]);
        float m3 = mish_f(h[3] * sc[3] + sh[3]);
        bf16x4 xb = { f2bf(m0), f2bf(m1), f2bf(m2), f2bf(m3) };
        *(bf16x4*)(dst + (size_t)v * NC + 4 * c4) = xb;
    }
}

// ---------------------------------------------------------------------------
// One Chebyshev step, bf16 in/out, fp32 arithmetic.
//   s = L @ src; dst = FIRST ? s : 2*s - prev.
// prev read is PLAIN (round-4 fix): slot k-2 is re-read by the final einsum;
// an NT hint here evicts it from L3 and costs a 200 MB HBM stream later.
// ---------------------------------------------------------------------------
template <bool FIRST>
__global__ void __launch_bounds__(256) cheb_step(
    const int* __restrict__ cols, const float* __restrict__ vals,
    const unsigned short* __restrict__ src, const unsigned short* __restrict__ prev,
    unsigned short* __restrict__ dst) {
    int lane = threadIdx.x & 63;
    int wave = threadIdx.x >> 6;
    int c8 = lane & 7, rg = lane >> 3;
    int tile0 = blockIdx.x * TILE;

    #pragma unroll
    for (int it = 0; it < 2; ++it) {
        int v = tile0 + wave * 16 + it * 8 + rg;
        const int* cp = cols + v * NDEG;
        const float* vp = vals + v * NDEG;
        i32x4u c03 = *(const i32x4u*)cp;
        i32x4u c47 = *(const i32x4u*)(cp + 4);
        int    cl8 = cp[8];
        f32x4u a03 = *(const f32x4u*)vp;
        f32x4u a47 = *(const f32x4u*)(vp + 4);
        float  al8 = vp[8];

        int   cj[NDEG] = { c03[0], c03[1], c03[2], c03[3],
                           c47[0], c47[1], c47[2], c47[3], cl8 };
        float aj[NDEG] = { a03[0], a03[1], a03[2], a03[3],
                           a47[0], a47[1], a47[2], a47[3], al8 };

        bf16x8 g[NDEG];
        #pragma unroll
        for (int j = 0; j < NDEG; ++j)
            g[j] = *(const bf16x8*)(src + (size_t)cj[j] * NC + c8 * 8);

        float s[8] = {0.f, 0.f, 0.f, 0.f, 0.f, 0.f, 0.f, 0.f};
        #pragma unroll
        for (int j = 0; j < NDEG; ++j)
            #pragma unroll
            for (int q = 0; q < 8; ++q) s[q] += aj[j] * bf2f(g[j][q]);

        bf16x8 xb;
        if (FIRST) {
            #pragma unroll
            for (int q = 0; q < 8; ++q) xb[q] = f2bf(s[q]);
        } else {
            bf16x8 p = *(const bf16x8*)(prev + (size_t)v * NC + c8 * 8);
            #pragma unroll
            for (int q = 0; q < 8; ++q) xb[q] = f2bf(2.f * s[q] - bf2f(p[q]));
        }
        *(bf16x8*)(dst + (size_t)v * NC + c8 * 8) = xb;
    }
}

// ---------------------------------------------------------------------------
// FUSED final dispatch: Chebyshev step k=7 (slot 7 kept in LDS only) + full
// einsum over k=0..7 with bias.
//   - A fragments: direct per-lane nontemporal global loads, register
//     double-buffered one FULL iteration ahead (vmcnt never stalls MFMA).
//   - W fragments: LDS double-buffer (lgkmcnt domain).
//   - X7: LDS, swizzled. out stores nontemporal (never re-read).
// ---------------------------------------------------------------------------
__global__ void __launch_bounds__(256) cheb7_gemm(
    const int* __restrict__ cols, const float* __restrict__ vals,
    const unsigned short* __restrict__ basis, const unsigned short* __restrict__ Wb,
    const float* __restrict__ bias, float* __restrict__ out) {
    __shared__ __align__(16) short X7[NC * NC];      // 8 KB
    __shared__ __align__(16) short Wl[2][NC * NC];   // 2 x 8 KB

    const int tid  = threadIdx.x;
    const int lane = tid & 63;
    const int wave = tid >> 6;
    const int c8 = lane & 7, rg = lane >> 3;         // cheb mapping
    const int m16 = lane & 15, qq = lane >> 4;       // MFMA fragment mapping
    const int tile0 = blockIdx.x * TILE;
    const int rW = tid >> 3, cW = tid & 7;           // W staging mapping

    // own A row for the einsum (same fragment values as the LDS path)
    const unsigned short* aptr = basis + (size_t)(tile0 + wave * 16 + m16) * NC;

    // ---- prologue: A(0) regs + W(0) staged; all in flight across gathers ----
    bf16x8 a0 = __builtin_nontemporal_load((const bf16x8*)(aptr + qq * 8));
    bf16x8 a1 = __builtin_nontemporal_load((const bf16x8*)(aptr + 32 + qq * 8));
    {
        bf16x8 w0 = *(const bf16x8*)(Wb + rW * NC + cW * 8);
        bf16x8 w1 = *(const bf16x8*)(Wb + (rW + 32) * NC + cW * 8);
        *(bf16x8*)&Wl[0][LDSOFF(rW, cW)] = w0;
        *(bf16x8*)&Wl[0][LDSOFF(rW + 32, cW)] = w1;
    }

    // ---- phase 1: Chebyshev k=7 for own rows -> X7 (LDS), no global write ----
    {
        const unsigned short* src = basis + (size_t)6 * SLOT;
        const unsigned short* prv = basis + (size_t)5 * SLOT;
        #pragma unroll
        for (int it = 0; it < 2; ++it) {
            int r = wave * 16 + it * 8 + rg;
            int v = tile0 + r;
            const int* cp = cols + v * NDEG;
            const float* vp = vals + v * NDEG;
            i32x4u c03 = *(const i32x4u*)cp;
            i32x4u c47 = *(const i32x4u*)(cp + 4);
            int    cl8 = cp[8];
            f32x4u a03 = *(const f32x4u*)vp;
            f32x4u a47 = *(const f32x4u*)(vp + 4);
            float  al8 = vp[8];

            int   cj[NDEG] = { c03[0], c03[1], c03[2], c03[3],
                               c47[0], c47[1], c47[2], c47[3], cl8 };
            float aj[NDEG] = { a03[0], a03[1], a03[2], a03[3],
                               a47[0], a47[1], a47[2], a47[3], al8 };

            bf16x8 g[NDEG];
            #pragma unroll
            for (int j = 0; j < NDEG; ++j)
                g[j] = *(const bf16x8*)(src + (size_t)cj[j] * NC + c8 * 8);

            float s[8] = {0.f, 0.f, 0.f, 0.f, 0.f, 0.f, 0.f, 0.f};
            #pragma unroll
            for (int j = 0; j < NDEG; ++j)
                #pragma unroll
                for (int q = 0; q < 8; ++q) s[q] += aj[j] * bf2f(g[j][q]);

            // plain (cached) prev load: slot 5 rows are re-read by einsum k=5
            bf16x8 p = *(const bf16x8*)(prv + (size_t)v * NC + c8 * 8);
            bf16x8 xb;
            #pragma unroll
            for (int q = 0; q < 8; ++q) xb[q] = f2bf(2.f * s[q] - bf2f(p[q]));
            *(bf16x8*)&X7[LDSOFF(r, c8)] = xb;
        }
    }
    __syncthreads();   // X7 + Wl[0] ready

    // ---- phase 2: einsum k=0..7; A reg-dbuf (vmcnt), W LDS-dbuf (lgkmcnt) ----
    f32x4 acc[4];
    #pragma unroll
    for (int nt = 0; nt < 4; ++nt) acc[nt] = (f32x4){0.f, 0.f, 0.f, 0.f};

    #pragma unroll
    for (int k = 0; k < NK; ++k) {
        bf16x8 na0, na1, nw0, nw1;
        if (k + 1 < NK) {
            if (k + 1 < NK - 1) {   // A(k+1); slot 7 comes from X7
                const unsigned short* ap = aptr + (size_t)(k + 1) * SLOT;
                na0 = __builtin_nontemporal_load((const bf16x8*)(ap + qq * 8));
                na1 = __builtin_nontemporal_load((const bf16x8*)(ap + 32 + qq * 8));
            }
            const unsigned short* wp = Wb + (k + 1) * NC * NC;
            nw0 = *(const bf16x8*)(wp + rW * NC + cW * 8);
            nw1 = *(const bf16x8*)(wp + (rW + 32) * NC + cW * 8);
        }
        // MFMAs: A from regs (retired last iter), W from LDS (lgkmcnt only)
        const short* wb = Wl[k & 1];
        #pragma unroll
        for (int nt = 0; nt < 4; ++nt) {
            int o = nt * 16 + m16;
            bf16x8 b0 = *(const bf16x8*)&wb[LDSOFF(o, qq)];
            bf16x8 b1 = *(const bf16x8*)&wb[LDSOFF(o, qq + 4)];
            acc[nt] = __builtin_amdgcn_mfma_f32_16x16x32_bf16(a0, b0, acc[nt], 0, 0, 0);
            acc[nt] = __builtin_amdgcn_mfma_f32_16x16x32_bf16(a1, b1, acc[nt], 0, 0, 0);
        }
        if (k + 1 < NK) {
            short* wn = Wl[(k + 1) & 1];
            *(bf16x8*)&wn[LDSOFF(rW, cW)] = nw0;
            *(bf16x8*)&wn[LDSOFF(rW + 32, cW)] = nw1;
            __syncthreads();
            if (k + 1 < NK - 1) {
                a0 = na0; a1 = na1;
            } else {                 // next is k=7: A from X7
                a0 = *(const bf16x8*)&X7[LDSOFF(wave * 16 + m16, qq)];
                a1 = *(const bf16x8*)&X7[LDSOFF(wave * 16 + m16, qq + 4)];
            }
        }
    }

    #pragma unroll
    for (int nt = 0; nt < 4; ++nt) {
        float bcol = bias[nt * 16 + m16];
        #pragma unroll
        for (int r = 0; r < 4; ++r) {
            int vout = tile0 + wave * 16 + qq * 4 + r;
            __builtin_nontemporal_store(acc[nt][r] + bcol,
                                        out + (size_t)vout * NC + nt * 16 + m16);
        }
    }
}

// ---------------------------------------------------------------------------
// Fallback einsum (small-ws path only): LDS-free grouped gemm.
// ---------------------------------------------------------------------------
__global__ void __launch_bounds__(256) gemm_bases(
    const unsigned short* __restrict__ basis, const unsigned short* __restrict__ Wb,
    const float* __restrict__ bias, float* __restrict__ out,
    int kb, int kc, int S, int first) {
    int lane = threadIdx.x & 63;
    int wave = threadIdx.x >> 6;
    int m16 = lane & 15, qq = lane >> 4;
    int tile0 = blockIdx.x * TILE;

    f32x4 acc[4];
    #pragma unroll
    for (int nt = 0; nt < 4; ++nt) acc[nt] = (f32x4){0.f, 0.f, 0.f, 0.f};

    #pragma unroll 1
    for (int j = 0; j < kc; ++j) {
        int k = kb + j;
        const unsigned short* bs =
            basis + (size_t)(k % S) * SLOT + (size_t)(tile0 + wave * 16 + m16) * NC;
        bf16x8 a0 = *(const bf16x8*)(bs + qq * 8);
        bf16x8 a1 = *(const bf16x8*)(bs + 32 + qq * 8);
        const unsigned short* wk = Wb + (size_t)k * NC * NC;
        #pragma unroll
        for (int nt = 0; nt < 4; ++nt) {
            const unsigned short* wr = wk + (nt * 16 + m16) * NC;
            bf16x8 b0 = *(const bf16x8*)(wr + qq * 8);
            bf16x8 b1 = *(const bf16x8*)(wr + 32 + qq * 8);
            acc[nt] = __builtin_amdgcn_mfma_f32_16x16x32_bf16(a0, b0, acc[nt], 0, 0, 0);
            acc[nt] = __builtin_amdgcn_mfma_f32_16x16x32_bf16(a1, b1, acc[nt], 0, 0, 0);
        }
    }

    #pragma unroll
    for (int nt = 0; nt < 4; ++nt) {
        float bcol = bias[nt * 16 + m16];
        #pragma unroll
        for (int r = 0; r < 4; ++r) {
            int vout = tile0 + wave * 16 + qq * 4 + r;
            float* po = out + (size_t)vout * NC + nt * 16 + m16;
            *po = first ? (acc[nt][r] + bcol) : (*po + acc[nt][r]);
        }
    }
}

// ---------------------------------------------------------------------------
// Inputs: (x, lap_rows, lap_cols, lap_vals, gamma, beta, weight, bias).
// lap_rows redundant (row-sorted, 9 nnz/row). cols delivered as int32.
// ws: stats[128]f32 @0 | Wb bf16[8*64*64] @1 KiB | basis ring @128 KiB.
// Primary path (S>=7): slots 0..6 materialized, slot 7 fused into final
// cheb7_gemm dispatch (LDS-only).
// ---------------------------------------------------------------------------
extern "C" void kernel_launch(void* const* d_in, const int* in_sizes, int n_in,
                              void* d_out, int out_size, void* d_ws, size_t ws_size,
                              hipStream_t stream) {
    const float* x      = (const float*)d_in[0];
    const int*   cols   = (const int*)  d_in[2];
    const float* vals   = (const float*)d_in[3];
    const float* gamma  = (const float*)d_in[4];
    const float* beta   = (const float*)d_in[5];
    const float* weight = (const float*)d_in[6];
    const float* bias   = (const float*)d_in[7];
    float* out = (float*)d_out;

    char* wsb = (char*)d_ws;
    float*          stats = (float*)wsb;
    unsigned short* Wb    = (unsigned short*)(wsb + 1024);
    unsigned short* basis = (unsigned short*)(wsb + 131072);

    long long Sll = ((long long)ws_size - 131072) / (long long)(SLOT * sizeof(unsigned short));
    int S = (Sll < 0) ? 0 : (int)Sll;
    if (S > NK) S = NK;
    if (S < 3) S = 3;

    hipMemsetAsync(stats, 0, 1024, stream);
    stats_wconv_kernel<<<1152, 256, 0, stream>>>(x, stats, weight, Wb);
    bn_mish_k0<<<NBLK, 256, 0, stream>>>(x, stats, gamma, beta, basis);  // slot 0

    if (S >= 7) {
        // slots 1..6 materialized; k=7 fused into the final gemm dispatch
        for (int k = 1; k < NK - 1; ++k) {
            const unsigned short* src = basis + (size_t)(k - 1) * SLOT;
            unsigned short*       dst = basis + (size_t)k * SLOT;
            if (k == 1) {
                cheb_step<true><<<NBLK, 256, 0, stream>>>(cols, vals, src, src, dst);
            } else {
                const unsigned short* prev = basis + (size_t)(k - 2) * SLOT;
                cheb_step<false><<<NBLK, 256, 0, stream>>>(cols, vals, src, prev, dst);
            }
        }
        cheb7_gemm<<<NBLK, 256, 0, stream>>>(cols, vals, basis, Wb, bias, out);
    } else {
        int kb = 0, gsize = S, first = 1;
        while (kb < NK) {
            int kc = (gsize < NK - kb) ? gsize : (NK - kb);
            for (int k = (kb == 0 ? 1 : kb); k < kb + kc; ++k) {
                const unsigned short* src = basis + (size_t)((k - 1) % S) * SLOT;
                unsigned short*       dst = basis + (size_t)(k % S) * SLOT;
                if (k == 1) {
                    cheb_step<true><<<NBLK, 256, 0, stream>>>(cols, vals, src, src, dst);
                } else {
                    const unsigned short* prev = basis + (size_t)((k - 2) % S) * SLOT;
                    cheb_step<false><<<NBLK, 256, 0, stream>>>(cols, vals, src, prev, dst);
                }
            }
            gemm_bases<<<NBLK, 256, 0, stream>>>(basis, Wb, bias, out, kb, kc, S, first);
            first = 0;
            kb += kc;
            gsize = S - 2;
        }
    }
}